// Round 11
// baseline (428.311 us; speedup 1.0000x reference)
//
#include <hip/hip_runtime.h>
#include <cstddef>
#include <cstdint>

// Bigram CE via MFMA (fp16 fragments). Row-slab: block = 16 consecutive rows,
// 1 block/CU (grid 256 x 1024 thr), 98 column windows of 1024. Per window:
// MFMA -> 64KB LDS tile -> each wave stores one row's 4KB run (nt full-line).
// In-loop barriers are lgkm-only (raw s_barrier, NO vmcnt drain) so nt stores
// stay in flight across windows; all vmem loads (W frags + bias) are
// register-prefetched one full window ahead (distance-1) so no load-use wait
// ever forces older stores to retire (in-order vmcnt).
// N=4096, V=100277, K=32.

using f32x4 = __attribute__((ext_vector_type(4))) float;
using f16x8 = __attribute__((ext_vector_type(8))) _Float16;

constexpr int N_ROWS  = 4096;
constexpr int ROWS_PB = 16;
constexpr int NBLK    = N_ROWS / ROWS_PB;      // 256 blocks = 1/CU
constexpr int WIN     = 1024;                  // cols per window
constexpr int NWIN    = 98;                    // 98*1024 = 100352 >= V
constexpr int TPB     = 1024;
constexpr int WAVES   = 16;
constexpr int TILES   = 4;                     // 16-col tiles per wave per window
constexpr int V_TILES = NWIN * (WIN / 16);     // 6272
constexpr int TSTR    = 1028;                  // LDS row stride (floats)

// d_ws layout (bytes)
constexpr size_t RS_OFF = 0;                               // rowsum 16KB
constexpr size_t EF_OFF = 64 * 1024;
constexpr size_t EF_BYTES = (size_t)NBLK * 64 * 16;        // 256 KB
constexpr size_t WF_OFF = EF_OFF + EF_BYTES;               // 6.42 MB

static __device__ __forceinline__ uint4 pack8h(const float* f) {
    unsigned short u[8];
#pragma unroll
    for (int i = 0; i < 8; ++i) {
        _Float16 h = (_Float16)f[i];
        u[i] = __builtin_bit_cast(unsigned short, h);
    }
    uint4 r;
    r.x = (unsigned)u[0] | ((unsigned)u[1] << 16);
    r.y = (unsigned)u[2] | ((unsigned)u[3] << 16);
    r.z = (unsigned)u[4] | ((unsigned)u[5] << 16);
    r.w = (unsigned)u[6] | ((unsigned)u[7] << 16);
    return r;
}

// W -> fp16 A-operand fragments. Lane l: col = tile*16 + (l&15), k=(l>>4)*8..+7.
__global__ __launch_bounds__(256) void prep_wfrag(
    const float* __restrict__ W, uint4* __restrict__ Wf, int V)
{
    const int g    = blockIdx.x * 256 + threadIdx.x;   // V_TILES*64
    const int lane = g & 63;
    const int tile = g >> 6;
    int col = tile * 16 + (lane & 15);
    if (col >= V) col = V - 1;                         // pad clamp (masked later)
    const int k0 = (lane >> 4) * 8;
    const float* wp = W + (size_t)col * 32 + k0;
    float f[8];
    *reinterpret_cast<float4*>(f)     = *reinterpret_cast<const float4*>(wp);
    *reinterpret_cast<float4*>(f + 4) = *reinterpret_cast<const float4*>(wp + 4);
    Wf[g] = pack8h(f);
}

// emb[seq] -> fp16 B-operand fragments. Lane l: n = l&15, k = (l>>4)*8..+7.
__global__ __launch_bounds__(256) void prep_efrag(
    const int* __restrict__ seq, const float* __restrict__ emb,
    uint4* __restrict__ Ef)
{
    const int g    = blockIdx.x * 256 + threadIdx.x;   // NBLK*64
    const int lane = g & 63;
    const int c    = g >> 6;
    const int row  = c * 16 + (lane & 15);
    const int k0   = (lane >> 4) * 8;
    const int idx  = seq[row];
    const float* ep = emb + (size_t)idx * 32 + k0;
    float f[8];
    *reinterpret_cast<float4*>(f)     = *reinterpret_cast<const float4*>(ep);
    *reinterpret_cast<float4*>(f + 4) = *reinterpret_cast<const float4*>(ep + 4);
    Ef[g] = pack8h(f);
}

__global__ __launch_bounds__(TPB) void bigram_main(
    const uint4* __restrict__ Wf,
    const float* __restrict__ bias,
    const uint4* __restrict__ Ef,
    float*       __restrict__ logits,
    float*       __restrict__ rowsum,
    int V)
{
    __shared__ float buf[ROWS_PB][TSTR];     // 65.8 KB
    __shared__ float lsum[WAVES][ROWS_PB];   // 1 KB

    const int tid  = threadIdx.x;
    const int lane = tid & 63;
    const int wid  = tid >> 6;
    const int lgrp = lane >> 4;
    const int lcol = lane & 15;
    const int b    = blockIdx.x;

    // emb fragments for this block's 16 rows: loop-invariant.
    const f16x8 E = __builtin_bit_cast(f16x8, Ef[(size_t)b * 64 + lane]);
    const int wcol = wid * (TILES * 16);       // wave's col offset inside window
    float rs = 0.f;

    // Prologue: load window 0's W fragments + bias (window 0 is never tail).
    uint4 Wc[TILES]; f32x4 Bc[TILES];
#pragma unroll
    for (int t = 0; t < TILES; ++t) {
        Wc[t] = Wf[(size_t)(wid * TILES + t) * 64 + lane];
        const float4 b4 = *reinterpret_cast<const float4*>(
            bias + wcol + t * 16 + lgrp * 4);
        Bc[t] = f32x4{b4.x, b4.y, b4.z, b4.w};
    }

    for (int s = 0; s < NWIN; ++s) {
        const int  cbase = s * WIN;
        const bool last  = (s == NWIN - 1);

        // ---- distance-1 prefetch of next window's W frags + bias ----
        const int  sp    = (s + 1 < NWIN) ? s + 1 : s;
        const bool ptail = (sp == NWIN - 1);
        uint4 Wn[TILES]; f32x4 Bn[TILES];
#pragma unroll
        for (int t = 0; t < TILES; ++t)
            Wn[t] = Wf[(size_t)(sp * (WIN / 16) + wid * TILES + t) * 64 + lane];
#pragma unroll
        for (int t = 0; t < TILES; ++t) {
            const int c0 = sp * WIN + wcol + t * 16 + lgrp * 4;
            if (!ptail) {
                const float4 b4 = *reinterpret_cast<const float4*>(bias + c0);
                Bn[t] = f32x4{b4.x, b4.y, b4.z, b4.w};
            } else {
#pragma unroll
                for (int j = 0; j < 4; ++j) {
                    const int c = c0 + j;
                    Bn[t][j] = bias[c < V ? c : V - 1];
                }
            }
        }

        // ---- compute phase: MFMA (bias as C-init) + exp + LDS write ----
#pragma unroll
        for (int t = 0; t < TILES; ++t) {
            const f32x4 acc = __builtin_amdgcn_mfma_f32_16x16x32_f16(
                __builtin_bit_cast(f16x8, Wc[t]), E, Bc[t], 0, 0, 0);
            // D: seq row = lane&15; vocab col = cbase + wcol + t*16 + lgrp*4 + j.
            if (!last) {
                rs += __expf(acc[0]) + __expf(acc[1]) +
                      __expf(acc[2]) + __expf(acc[3]);
            } else {
                const int c0 = cbase + wcol + t * 16 + lgrp * 4;
#pragma unroll
                for (int j = 0; j < 4; ++j)
                    if (c0 + j < V) rs += __expf(acc[j]);
            }
            *reinterpret_cast<f32x4*>(&buf[lcol][wcol + t * 16 + lgrp * 4]) = acc;
        }

        // lgkm-only barrier: LDS writes visible; nt stores stay in flight.
        asm volatile("s_waitcnt lgkmcnt(0)" ::: "memory");
        __builtin_amdgcn_s_barrier();
        __builtin_amdgcn_sched_barrier(0);

        // ---- store phase: wave w stores row w's 4KB run (nt, full lines) ----
        {
            const int n = b * ROWS_PB + wid;
            float* dst = logits + (size_t)n * V + cbase;
#pragma unroll
            for (int i = 0; i < 4; ++i) {
                const int colL = i * 256 + lane * 4;
                const f32x4 v = *reinterpret_cast<const f32x4*>(&buf[wid][colL]);
                if (!last) {
                    __builtin_nontemporal_store(v, reinterpret_cast<f32x4*>(dst + colL));
                } else {
                    const int cg = cbase + colL;
                    if (cg + 3 < V) {
                        __builtin_nontemporal_store(v, reinterpret_cast<f32x4*>(dst + colL));
                    } else {
#pragma unroll
                        for (int j = 0; j < 4; ++j)
                            if (cg + j < V)
                                __builtin_nontemporal_store(v[j], dst + colL + j);
                    }
                }
            }
        }

        // lgkm-only barrier: all ds_reads done before next window overwrites buf.
        asm volatile("s_waitcnt lgkmcnt(0)" ::: "memory");
        __builtin_amdgcn_s_barrier();
        __builtin_amdgcn_sched_barrier(0);

#pragma unroll
        for (int t = 0; t < TILES; ++t) { Wc[t] = Wn[t]; Bc[t] = Bn[t]; }
    }

    // In-block rowsum: lane's rs covers row lcol over this wave's col slices.
    rs += __shfl_xor(rs, 16, 64);
    rs += __shfl_xor(rs, 32, 64);
    if (lane < 16) lsum[wid][lcol] = rs;
    __syncthreads();
    if (tid < ROWS_PB) {
        float t = 0.f;
#pragma unroll
        for (int w = 0; w < WAVES; ++w) t += lsum[w][tid];
        rowsum[b * ROWS_PB + tid] = t;
    }
}

// loss = mean( log(rowsum[n]) - (dot(emb[seq[n]], W[pred[n]]) + b[pred[n]]) )
__global__ void bigram_loss(
    const int*   __restrict__ seq,
    const int*   __restrict__ pred,
    const float* __restrict__ emb,
    const float* __restrict__ W,
    const float* __restrict__ bias,
    const float* __restrict__ rowsum,
    float*       __restrict__ loss,
    int N)
{
    const int tid = threadIdx.x;
    float local = 0.f;
    for (int n = blockIdx.x * blockDim.x + tid; n < N; n += gridDim.x * blockDim.x) {
        const int r = seq[n], t = pred[n];
        const float4* e4 = reinterpret_cast<const float4*>(emb + (size_t)r * 32);
        const float4* w4 = reinterpret_cast<const float4*>(W + (size_t)t * 32);
        float d = bias[t];
#pragma unroll
        for (int i = 0; i < 8; ++i) {
            const float4 e = e4[i], w = w4[i];
            d += e.x * w.x + e.y * w.y + e.z * w.z + e.w * w.w;
        }
        local += __logf(rowsum[n]) - d;
    }
#pragma unroll
    for (int off = 32; off >= 1; off >>= 1) local += __shfl_xor(local, off, 64);
    __shared__ float r4[4];
    if ((tid & 63) == 0) r4[tid >> 6] = local;
    __syncthreads();
    if (tid == 0) {
        const float s = r4[0] + r4[1] + r4[2] + r4[3];
        atomicAdd(loss, s / (float)N);
    }
}

extern "C" void kernel_launch(void* const* d_in, const int* in_sizes, int n_in,
                              void* d_out, int out_size, void* d_ws, size_t ws_size,
                              hipStream_t stream)
{
    const int*   seq  = (const int*)d_in[0];
    const int*   pred = (const int*)d_in[1];
    const float* emb  = (const float*)d_in[2];
    const float* W    = (const float*)d_in[3];
    const float* bias = (const float*)d_in[4];

    const int N = in_sizes[0];      // 4096
    const int V = in_sizes[4];      // 100277

    float* logits = (float*)d_out;
    float* loss   = logits + (size_t)N * V;

    char*  ws     = (char*)d_ws;
    float* rowsum = (float*)(ws + RS_OFF);
    uint4* Ef     = (uint4*)(ws + EF_OFF);
    uint4* Wf     = (uint4*)(ws + WF_OFF);

    hipMemsetAsync((void*)loss, 0, sizeof(float), stream);

    hipLaunchKernelGGL(prep_wfrag, dim3(V_TILES * 64 / 256), dim3(256), 0, stream,
                       W, Wf, V);
    hipLaunchKernelGGL(prep_efrag, dim3(NBLK * 64 / 256), dim3(256), 0, stream,
                       seq, emb, Ef);

    hipLaunchKernelGGL(bigram_main, dim3(NBLK), dim3(TPB), 0, stream,
                       Wf, bias, Ef, logits, rowsum, V);

    hipLaunchKernelGGL(bigram_loss, dim3(16), dim3(256), 0, stream,
                       seq, pred, emb, W, bias, rowsum, loss, N);
}

// Round 12
// 392.132 us; speedup vs baseline: 1.0923x; 1.0923x over previous
//
#include <hip/hip_runtime.h>
#include <cstddef>
#include <cstdint>

// Bigram CE via MFMA (fp16 fragments). Row-slab: block = 16 consecutive rows,
// 1 block/CU (grid 256 x 1024 thr), 98 column windows of 1024.
// This round: 128B-ALIGNED nt stores. Row n's stores are shifted left by
// L = (21*n) mod 32 floats so every 1KB nt packet covers exactly 8 full
// 128B lines (V*4 % 128 = 84 -> rows are misaligned by a per-row amount).
// The first L floats of each window's run come from the previous window via
// a 32-float double-slotted carry in LDS. lgkm-only barriers (no vmcnt drain).
// N=4096, V=100277, K=32.

using f32x4 = __attribute__((ext_vector_type(4))) float;
using f16x8 = __attribute__((ext_vector_type(8))) _Float16;

constexpr int N_ROWS  = 4096;
constexpr int ROWS_PB = 16;
constexpr int NBLK    = N_ROWS / ROWS_PB;      // 256 blocks = 1/CU
constexpr int WIN     = 1024;                  // cols per window
constexpr int NWIN    = 98;                    // 98*1024 = 100352 >= V
constexpr int TPB     = 1024;
constexpr int WAVES   = 16;
constexpr int TILES   = 4;                     // 16-col tiles per wave per window
constexpr int V_TILES = NWIN * (WIN / 16);     // 6272
constexpr int PSTR    = 64 + WIN + 4;          // LDS row stride: 2 carry slots + data

// d_ws layout (bytes)
constexpr size_t RS_OFF = 0;                               // rowsum 16KB
constexpr size_t EF_OFF = 64 * 1024;
constexpr size_t EF_BYTES = (size_t)NBLK * 64 * 16;        // 256 KB
constexpr size_t WF_OFF = EF_OFF + EF_BYTES;               // 6.42 MB

static __device__ __forceinline__ uint4 pack8h(const float* f) {
    unsigned short u[8];
#pragma unroll
    for (int i = 0; i < 8; ++i) {
        _Float16 h = (_Float16)f[i];
        u[i] = __builtin_bit_cast(unsigned short, h);
    }
    uint4 r;
    r.x = (unsigned)u[0] | ((unsigned)u[1] << 16);
    r.y = (unsigned)u[2] | ((unsigned)u[3] << 16);
    r.z = (unsigned)u[4] | ((unsigned)u[5] << 16);
    r.w = (unsigned)u[6] | ((unsigned)u[7] << 16);
    return r;
}

// Merged prep: W -> fp16 A-operand fragments, then emb[seq] -> fp16 B-frags.
__global__ __launch_bounds__(256) void prep_frags(
    const float* __restrict__ W,
    const int*   __restrict__ seq,
    const float* __restrict__ emb,
    uint4* __restrict__ Wf,
    uint4* __restrict__ Ef,
    int V)
{
    const int g = blockIdx.x * 256 + threadIdx.x;
    if (g < V_TILES * 64) {
        const int lane = g & 63;
        const int tile = g >> 6;
        int col = tile * 16 + (lane & 15);
        if (col >= V) col = V - 1;                     // pad clamp (masked later)
        const int k0 = (lane >> 4) * 8;
        const float* wp = W + (size_t)col * 32 + k0;
        float f[8];
        *reinterpret_cast<float4*>(f)     = *reinterpret_cast<const float4*>(wp);
        *reinterpret_cast<float4*>(f + 4) = *reinterpret_cast<const float4*>(wp + 4);
        Wf[g] = pack8h(f);
    } else {
        const int g2   = g - V_TILES * 64;             // NBLK*64
        const int lane = g2 & 63;
        const int c    = g2 >> 6;
        const int row  = c * 16 + (lane & 15);
        const int k0   = (lane >> 4) * 8;
        const int idx  = seq[row];
        const float* ep = emb + (size_t)idx * 32 + k0;
        float f[8];
        *reinterpret_cast<float4*>(f)     = *reinterpret_cast<const float4*>(ep);
        *reinterpret_cast<float4*>(f + 4) = *reinterpret_cast<const float4*>(ep + 4);
        Ef[g2] = pack8h(f);
    }
}

__global__ __launch_bounds__(TPB) void bigram_main(
    const uint4* __restrict__ Wf,
    const float* __restrict__ bias,
    const uint4* __restrict__ Ef,
    float*       __restrict__ logits,
    float*       __restrict__ rowsum,
    int V)
{
    __shared__ float ebuf[ROWS_PB][PSTR];    // ~70 KB: [0,32)=C0 [32,64)=C1 [64,..)=D
    __shared__ float lsum[WAVES][ROWS_PB];

    const int tid  = threadIdx.x;
    const int lane = tid & 63;
    const int wid  = tid >> 6;
    const int lgrp = lane >> 4;
    const int lcol = lane & 15;
    const int b    = blockIdx.x;

    const f16x8 E = __builtin_bit_cast(f16x8, Ef[(size_t)b * 64 + lane]);
    const int wcol = wid * (TILES * 16);
    float rs = 0.f;

    // This wave stores row n_row with left-shift L (row misalignment in floats).
    const int n_row = b * ROWS_PB + wid;
    const int Lsh   = (21 * n_row) & 31;     // (n*V*4 mod 128)/4
    float* rowbase  = logits + (size_t)n_row * V;

    // Prologue: window 0 W frags + bias (window 0 never tail).
    uint4 Wc[TILES]; f32x4 Bc[TILES];
#pragma unroll
    for (int t = 0; t < TILES; ++t) {
        Wc[t] = Wf[(size_t)(wid * TILES + t) * 64 + lane];
        const float4 b4 = *reinterpret_cast<const float4*>(
            bias + wcol + t * 16 + lgrp * 4);
        Bc[t] = f32x4{b4.x, b4.y, b4.z, b4.w};
    }

    for (int s = 0; s < NWIN; ++s) {
        const int  cbase = s * WIN;
        const bool last  = (s == NWIN - 1);

        // ---- distance-1 prefetch of next window's W frags + bias ----
        const int  sp    = (s + 1 < NWIN) ? s + 1 : s;
        const bool ptail = (sp == NWIN - 1);
        uint4 Wn[TILES]; f32x4 Bn[TILES];
#pragma unroll
        for (int t = 0; t < TILES; ++t)
            Wn[t] = Wf[(size_t)(sp * (WIN / 16) + wid * TILES + t) * 64 + lane];
#pragma unroll
        for (int t = 0; t < TILES; ++t) {
            const int c0 = sp * WIN + wcol + t * 16 + lgrp * 4;
            if (!ptail) {
                const float4 b4 = *reinterpret_cast<const float4*>(bias + c0);
                Bn[t] = f32x4{b4.x, b4.y, b4.z, b4.w};
            } else {
#pragma unroll
                for (int j = 0; j < 4; ++j) {
                    const int c = c0 + j;
                    Bn[t][j] = bias[c < V ? c : V - 1];
                }
            }
        }

        // ---- compute: MFMA (bias C-init) + exp + LDS write (row = lcol) ----
#pragma unroll
        for (int t = 0; t < TILES; ++t) {
            const f32x4 acc = __builtin_amdgcn_mfma_f32_16x16x32_f16(
                __builtin_bit_cast(f16x8, Wc[t]), E, Bc[t], 0, 0, 0);
            if (!last) {
                rs += __expf(acc[0]) + __expf(acc[1]) +
                      __expf(acc[2]) + __expf(acc[3]);
            } else {
                const int c0 = cbase + wcol + t * 16 + lgrp * 4;
#pragma unroll
                for (int j = 0; j < 4; ++j)
                    if (c0 + j < V) rs += __expf(acc[j]);
            }
            *reinterpret_cast<f32x4*>(&ebuf[lcol][64 + wcol + t * 16 + lgrp * 4]) = acc;
        }

        asm volatile("s_waitcnt lgkmcnt(0)" ::: "memory");
        __builtin_amdgcn_s_barrier();
        __builtin_amdgcn_sched_barrier(0);

        // ---- store phase: wave w stores row w's ALIGNED 4KB run ----
        {
            const int slotCur = (s & 1) * 32;     // prefix slot for this window
#pragma unroll
            for (int i = 0; i < 4; ++i) {
                const int colL = i * 256 + lane * 4;
                float v[4];
                if (i == 0) {
#pragma unroll
                    for (int j = 0; j < 4; ++j) {
                        const int idx = colL + j;
                        int a = 64 + idx - Lsh;
                        if (idx < Lsh && slotCur == 0) a -= 32;  // even-window prefix at [0,32)
                        v[j] = ebuf[wid][a];
                    }
                } else {
#pragma unroll
                    for (int j = 0; j < 4; ++j)
                        v[j] = ebuf[wid][64 + colL + j - Lsh];
                }
                const int gcol = cbase - Lsh + colL;
                if (s == 0 && i == 0) {
#pragma unroll
                    for (int j = 0; j < 4; ++j)
                        if (gcol + j >= 0)
                            __builtin_nontemporal_store(v[j], rowbase + gcol + j);
                } else if (last && i == 3) {
#pragma unroll
                    for (int j = 0; j < 4; ++j)
                        if (gcol + j < V)
                            __builtin_nontemporal_store(v[j], rowbase + gcol + j);
                } else {
                    __builtin_nontemporal_store(
                        f32x4{v[0], v[1], v[2], v[3]},
                        reinterpret_cast<f32x4*>(rowbase + gcol));
                }
            }
            // Carry: last 32 cols of this window -> other prefix slot (for s+1).
            if (lane < 32) {
                const float cv = ebuf[wid][64 + WIN - 32 + lane];
                ebuf[wid][((s + 1) & 1) * 32 + lane] = cv;
            }
        }

        asm volatile("s_waitcnt lgkmcnt(0)" ::: "memory");
        __builtin_amdgcn_s_barrier();
        __builtin_amdgcn_sched_barrier(0);

#pragma unroll
        for (int t = 0; t < TILES; ++t) { Wc[t] = Wn[t]; Bc[t] = Bn[t]; }
    }

    // In-block rowsum.
    rs += __shfl_xor(rs, 16, 64);
    rs += __shfl_xor(rs, 32, 64);
    if (lane < 16) lsum[wid][lcol] = rs;
    __syncthreads();
    if (tid < ROWS_PB) {
        float t = 0.f;
#pragma unroll
        for (int w = 0; w < WAVES; ++w) t += lsum[w][tid];
        rowsum[b * ROWS_PB + tid] = t;
    }
}

// Single-block loss: no atomics, no memset.
// loss = mean( log(rowsum[n]) - (dot(emb[seq[n]], W[pred[n]]) + b[pred[n]]) )
__global__ __launch_bounds__(1024) void bigram_loss(
    const int*   __restrict__ seq,
    const int*   __restrict__ pred,
    const float* __restrict__ emb,
    const float* __restrict__ W,
    const float* __restrict__ bias,
    const float* __restrict__ rowsum,
    float*       __restrict__ loss,
    int N)
{
    const int tid = threadIdx.x;
    float local = 0.f;
    for (int n = tid; n < N; n += 1024) {
        const int r = seq[n], t = pred[n];
        const float4* e4 = reinterpret_cast<const float4*>(emb + (size_t)r * 32);
        const float4* w4 = reinterpret_cast<const float4*>(W + (size_t)t * 32);
        float d = bias[t];
#pragma unroll
        for (int i = 0; i < 8; ++i) {
            const float4 e = e4[i], w = w4[i];
            d += e.x * w.x + e.y * w.y + e.z * w.z + e.w * w.w;
        }
        local += __logf(rowsum[n]) - d;
    }
#pragma unroll
    for (int off = 32; off >= 1; off >>= 1) local += __shfl_xor(local, off, 64);
    __shared__ float r16[16];
    if ((tid & 63) == 0) r16[tid >> 6] = local;
    __syncthreads();
    if (tid == 0) {
        float s = 0.f;
#pragma unroll
        for (int w = 0; w < 16; ++w) s += r16[w];
        loss[0] = s / (float)N;
    }
}

extern "C" void kernel_launch(void* const* d_in, const int* in_sizes, int n_in,
                              void* d_out, int out_size, void* d_ws, size_t ws_size,
                              hipStream_t stream)
{
    const int*   seq  = (const int*)d_in[0];
    const int*   pred = (const int*)d_in[1];
    const float* emb  = (const float*)d_in[2];
    const float* W    = (const float*)d_in[3];
    const float* bias = (const float*)d_in[4];

    const int N = in_sizes[0];      // 4096
    const int V = in_sizes[4];      // 100277

    float* logits = (float*)d_out;
    float* loss   = logits + (size_t)N * V;

    char*  ws     = (char*)d_ws;
    float* rowsum = (float*)(ws + RS_OFF);
    uint4* Ef     = (uint4*)(ws + EF_OFF);
    uint4* Wf     = (uint4*)(ws + WF_OFF);

    const int prepTotal = V_TILES * 64 + NBLK * 64;   // 417792 -> 1632 blocks
    hipLaunchKernelGGL(prep_frags, dim3(prepTotal / 256), dim3(256), 0, stream,
                       W, seq, emb, Wf, Ef, V);

    hipLaunchKernelGGL(bigram_main, dim3(NBLK), dim3(TPB), 0, stream,
                       Wf, bias, Ef, logits, rowsum, V);

    hipLaunchKernelGGL(bigram_loss, dim3(1), dim3(1024), 0, stream,
                       seq, pred, emb, W, bias, rowsum, loss, N);
}

// Round 13
// 363.978 us; speedup vs baseline: 1.1767x; 1.0773x over previous
//
#include <hip/hip_runtime.h>
#include <cstddef>
#include <cstdint>

// Bigram CE via MFMA (fp16 fragments). Row-slab: block = 16 consecutive rows,
// 1 block/CU (grid 256 x 1024 thr), 98 column windows of 1024.
// Round 13: DOUBLE-BUFFERED LDS tile -> ONE lgkm-only barrier per window.
// compute(s)->buf[s&1] | barrier | store(s) from buf[s&1] (nt, 128B-aligned
// via per-row shift L=(21*n)&31 with 32-float carry) || compute(s+1)->buf[~s&1].
// Stores keep a full window of slack; no vmcnt drain anywhere in the loop.
// N=4096, V=100277, K=32.

using f32x4 = __attribute__((ext_vector_type(4))) float;
using f16x8 = __attribute__((ext_vector_type(8))) _Float16;

constexpr int N_ROWS  = 4096;
constexpr int ROWS_PB = 16;
constexpr int NBLK    = N_ROWS / ROWS_PB;      // 256 blocks = 1/CU
constexpr int WIN     = 1024;                  // cols per window
constexpr int NWIN    = 98;                    // 98*1024 = 100352 >= V
constexpr int TPB     = 1024;
constexpr int WAVES   = 16;
constexpr int TILES   = 4;                     // 16-col tiles per wave per window
constexpr int V_TILES = NWIN * (WIN / 16);     // 6272
constexpr int PSTR    = 32 + WIN + 4;          // 1060: prefix [0,32) + data [32,32+WIN)

// d_ws layout (bytes)
constexpr size_t RS_OFF = 0;                               // rowsum 16KB
constexpr size_t EF_OFF = 64 * 1024;
constexpr size_t EF_BYTES = (size_t)NBLK * 64 * 16;        // 256 KB
constexpr size_t WF_OFF = EF_OFF + EF_BYTES;               // 6.42 MB

static __device__ __forceinline__ uint4 pack8h(const float* f) {
    unsigned short u[8];
#pragma unroll
    for (int i = 0; i < 8; ++i) {
        _Float16 h = (_Float16)f[i];
        u[i] = __builtin_bit_cast(unsigned short, h);
    }
    uint4 r;
    r.x = (unsigned)u[0] | ((unsigned)u[1] << 16);
    r.y = (unsigned)u[2] | ((unsigned)u[3] << 16);
    r.z = (unsigned)u[4] | ((unsigned)u[5] << 16);
    r.w = (unsigned)u[6] | ((unsigned)u[7] << 16);
    return r;
}

// Merged prep: W -> fp16 A-operand fragments, then emb[seq] -> fp16 B-frags.
__global__ __launch_bounds__(256) void prep_frags(
    const float* __restrict__ W,
    const int*   __restrict__ seq,
    const float* __restrict__ emb,
    uint4* __restrict__ Wf,
    uint4* __restrict__ Ef,
    int V)
{
    const int g = blockIdx.x * 256 + threadIdx.x;
    if (g < V_TILES * 64) {
        const int lane = g & 63;
        const int tile = g >> 6;
        int col = tile * 16 + (lane & 15);
        if (col >= V) col = V - 1;                     // pad clamp (masked later)
        const int k0 = (lane >> 4) * 8;
        const float* wp = W + (size_t)col * 32 + k0;
        float f[8];
        *reinterpret_cast<float4*>(f)     = *reinterpret_cast<const float4*>(wp);
        *reinterpret_cast<float4*>(f + 4) = *reinterpret_cast<const float4*>(wp + 4);
        Wf[g] = pack8h(f);
    } else {
        const int g2   = g - V_TILES * 64;             // NBLK*64
        const int lane = g2 & 63;
        const int c    = g2 >> 6;
        const int row  = c * 16 + (lane & 15);
        const int k0   = (lane >> 4) * 8;
        const int idx  = seq[row];
        const float* ep = emb + (size_t)idx * 32 + k0;
        float f[8];
        *reinterpret_cast<float4*>(f)     = *reinterpret_cast<const float4*>(ep);
        *reinterpret_cast<float4*>(f + 4) = *reinterpret_cast<const float4*>(ep + 4);
        Ef[g2] = pack8h(f);
    }
}

__global__ __launch_bounds__(TPB) void bigram_main(
    const uint4* __restrict__ Wf,
    const float* __restrict__ bias,
    const uint4* __restrict__ Ef,
    float*       __restrict__ logits,
    float*       __restrict__ rowsum,
    int V)
{
    __shared__ float ebuf[2][ROWS_PB][PSTR];   // ~136 KB
    __shared__ float lsum[WAVES][ROWS_PB];

    const int tid  = threadIdx.x;
    const int lane = tid & 63;
    const int wid  = tid >> 6;
    const int lgrp = lane >> 4;
    const int lcol = lane & 15;
    const int b    = blockIdx.x;

    const f16x8 E = __builtin_bit_cast(f16x8, Ef[(size_t)b * 64 + lane]);
    const int wcol = wid * (TILES * 16);
    float rs = 0.f;

    // This wave stores row n_row with left-shift L (row misalignment in floats).
    const int n_row = b * ROWS_PB + wid;
    const int Lsh   = (21 * n_row) & 31;     // (n*V*4 mod 128)/4
    float* rowbase  = logits + (size_t)n_row * V;

    // Prologue: window 0 W frags + bias (window 0 never tail).
    uint4 Wc[TILES]; f32x4 Bc[TILES];
#pragma unroll
    for (int t = 0; t < TILES; ++t) {
        Wc[t] = Wf[(size_t)(wid * TILES + t) * 64 + lane];
        const float4 b4 = *reinterpret_cast<const float4*>(
            bias + wcol + t * 16 + lgrp * 4);
        Bc[t] = f32x4{b4.x, b4.y, b4.z, b4.w};
    }

    for (int s = 0; s < NWIN; ++s) {
        const int  cbase = s * WIN;
        const bool last  = (s == NWIN - 1);
        float (*cbuf)[PSTR] = ebuf[s & 1];         // compute+store buffer
        float (*nbuf)[PSTR] = ebuf[(s + 1) & 1];   // next buffer (carry dest)

        // ---- distance-1 prefetch of next window's W frags + bias ----
        const int  sp    = (s + 1 < NWIN) ? s + 1 : s;
        const bool ptail = (sp == NWIN - 1);
        uint4 Wn[TILES]; f32x4 Bn[TILES];
#pragma unroll
        for (int t = 0; t < TILES; ++t)
            Wn[t] = Wf[(size_t)(sp * (WIN / 16) + wid * TILES + t) * 64 + lane];
#pragma unroll
        for (int t = 0; t < TILES; ++t) {
            const int c0 = sp * WIN + wcol + t * 16 + lgrp * 4;
            if (!ptail) {
                const float4 b4 = *reinterpret_cast<const float4*>(bias + c0);
                Bn[t] = f32x4{b4.x, b4.y, b4.z, b4.w};
            } else {
#pragma unroll
                for (int j = 0; j < 4; ++j) {
                    const int c = c0 + j;
                    Bn[t][j] = bias[c < V ? c : V - 1];
                }
            }
        }

        // ---- compute: MFMA (bias C-init) + exp + LDS write (row = lcol) ----
#pragma unroll
        for (int t = 0; t < TILES; ++t) {
            const f32x4 acc = __builtin_amdgcn_mfma_f32_16x16x32_f16(
                __builtin_bit_cast(f16x8, Wc[t]), E, Bc[t], 0, 0, 0);
            if (!last) {
                rs += __expf(acc[0]) + __expf(acc[1]) +
                      __expf(acc[2]) + __expf(acc[3]);
            } else {
                const int c0 = cbase + wcol + t * 16 + lgrp * 4;
#pragma unroll
                for (int j = 0; j < 4; ++j)
                    if (c0 + j < V) rs += __expf(acc[j]);
            }
            *reinterpret_cast<f32x4*>(&cbuf[lcol][32 + wcol + t * 16 + lgrp * 4]) = acc;
        }

        // The ONLY barrier per window: all LDS writes to cbuf visible, and all
        // waves' prior LDS reads (store s-1 from nbuf) completed.
        asm volatile("s_waitcnt lgkmcnt(0)" ::: "memory");
        __builtin_amdgcn_s_barrier();
        __builtin_amdgcn_sched_barrier(0);

        // ---- store phase: wave w stores row w's ALIGNED 4KB run from cbuf.
        //      Unified read addr: 32 + idx - Lsh (prefix [0,32) holds the carry).
        {
#pragma unroll
            for (int i = 0; i < 4; ++i) {
                const int colL = i * 256 + lane * 4;
                float v[4];
#pragma unroll
                for (int j = 0; j < 4; ++j)
                    v[j] = cbuf[wid][32 + colL + j - Lsh];
                const int gcol = cbase - Lsh + colL;
                if (s == 0 && i == 0) {
#pragma unroll
                    for (int j = 0; j < 4; ++j)
                        if (gcol + j >= 0)
                            __builtin_nontemporal_store(v[j], rowbase + gcol + j);
                } else if (last && i == 3) {
#pragma unroll
                    for (int j = 0; j < 4; ++j)
                        if (gcol + j < V)
                            __builtin_nontemporal_store(v[j], rowbase + gcol + j);
                } else {
                    __builtin_nontemporal_store(
                        f32x4{v[0], v[1], v[2], v[3]},
                        reinterpret_cast<f32x4*>(rowbase + gcol));
                }
            }
            // Carry: last 32 cols of this window -> next buffer's prefix slot.
            if (lane < 32)
                nbuf[wid][lane] = cbuf[wid][32 + WIN - 32 + lane];
        }
        // NO second barrier: compute(s+1) targets nbuf, whose last cross-wave
        // readers (store s-1) were ordered by the previous barrier.

#pragma unroll
        for (int t = 0; t < TILES; ++t) { Wc[t] = Wn[t]; Bc[t] = Bn[t]; }
    }

    // In-block rowsum.
    rs += __shfl_xor(rs, 16, 64);
    rs += __shfl_xor(rs, 32, 64);
    if (lane < 16) lsum[wid][lcol] = rs;
    __syncthreads();
    if (tid < ROWS_PB) {
        float t = 0.f;
#pragma unroll
        for (int w = 0; w < WAVES; ++w) t += lsum[w][tid];
        rowsum[b * ROWS_PB + tid] = t;
    }
}

// Single-block loss: no atomics, no memset.
// loss = mean( log(rowsum[n]) - (dot(emb[seq[n]], W[pred[n]]) + b[pred[n]]) )
__global__ __launch_bounds__(1024) void bigram_loss(
    const int*   __restrict__ seq,
    const int*   __restrict__ pred,
    const float* __restrict__ emb,
    const float* __restrict__ W,
    const float* __restrict__ bias,
    const float* __restrict__ rowsum,
    float*       __restrict__ loss,
    int N)
{
    const int tid = threadIdx.x;
    float local = 0.f;
    for (int n = tid; n < N; n += 1024) {
        const int r = seq[n], t = pred[n];
        const float4* e4 = reinterpret_cast<const float4*>(emb + (size_t)r * 32);
        const float4* w4 = reinterpret_cast<const float4*>(W + (size_t)t * 32);
        float d = bias[t];
#pragma unroll
        for (int i = 0; i < 8; ++i) {
            const float4 e = e4[i], w = w4[i];
            d += e.x * w.x + e.y * w.y + e.z * w.z + e.w * w.w;
        }
        local += __logf(rowsum[n]) - d;
    }
#pragma unroll
    for (int off = 32; off >= 1; off >>= 1) local += __shfl_xor(local, off, 64);
    __shared__ float r16[16];
    if ((tid & 63) == 0) r16[tid >> 6] = local;
    __syncthreads();
    if (tid == 0) {
        float s = 0.f;
#pragma unroll
        for (int w = 0; w < 16; ++w) s += r16[w];
        loss[0] = s / (float)N;
    }
}

extern "C" void kernel_launch(void* const* d_in, const int* in_sizes, int n_in,
                              void* d_out, int out_size, void* d_ws, size_t ws_size,
                              hipStream_t stream)
{
    const int*   seq  = (const int*)d_in[0];
    const int*   pred = (const int*)d_in[1];
    const float* emb  = (const float*)d_in[2];
    const float* W    = (const float*)d_in[3];
    const float* bias = (const float*)d_in[4];

    const int N = in_sizes[0];      // 4096
    const int V = in_sizes[4];      // 100277

    float* logits = (float*)d_out;
    float* loss   = logits + (size_t)N * V;

    char*  ws     = (char*)d_ws;
    float* rowsum = (float*)(ws + RS_OFF);
    uint4* Ef     = (uint4*)(ws + EF_OFF);
    uint4* Wf     = (uint4*)(ws + WF_OFF);

    const int prepTotal = V_TILES * 64 + NBLK * 64;   // 417792 -> 1632 blocks
    hipLaunchKernelGGL(prep_frags, dim3(prepTotal / 256), dim3(256), 0, stream,
                       W, seq, emb, Wf, Ef, V);

    hipLaunchKernelGGL(bigram_main, dim3(NBLK), dim3(TPB), 0, stream,
                       Wf, bias, Ef, logits, rowsum, V);

    hipLaunchKernelGGL(bigram_loss, dim3(1), dim3(1024), 0, stream,
                       seq, pred, emb, W, bias, rowsum, loss, N);
}

// Round 14
// 363.350 us; speedup vs baseline: 1.1788x; 1.0017x over previous
//
#include <hip/hip_runtime.h>
#include <cstddef>
#include <cstdint>

// Bigram CE via MFMA (fp16 fragments). Row-slab: block = 16 consecutive rows,
// 1 block/CU (grid 256 x 1024 thr), 98 column windows of 1024.
// Round 14: rotation moved to LDS WRITE side (per-lane row shift, b32 writes,
// ~2-way banks) so the store phase reads aligned ds_read_b128 (conflict-free)
// and issues nt 128B-aligned full-line stores immediately. Double-buffered
// LDS, ONE lgkm-only barrier per window, no vmcnt drain in the loop.
// N=4096, V=100277, K=32.

using f32x4 = __attribute__((ext_vector_type(4))) float;
using f16x8 = __attribute__((ext_vector_type(8))) _Float16;

constexpr int N_ROWS  = 4096;
constexpr int ROWS_PB = 16;
constexpr int NBLK    = N_ROWS / ROWS_PB;      // 256 blocks = 1/CU
constexpr int WIN     = 1024;                  // cols per window
constexpr int NWIN    = 98;                    // 98*1024 = 100352 >= V
constexpr int TPB     = 1024;
constexpr int WAVES   = 16;
constexpr int TILES   = 4;                     // 16-col tiles per wave per window
constexpr int V_TILES = NWIN * (WIN / 16);     // 6272
// LDS row stride: prefix [0,32) + data [32,1056) + tail spill [1056,1088).
// 1092 = 0 mod 4 (b128-aligned reads), = 4 mod 32 (write-bank decorrelation).
constexpr int PSTR    = 1092;

// d_ws layout (bytes)
constexpr size_t RS_OFF = 0;                               // rowsum 16KB
constexpr size_t EF_OFF = 64 * 1024;
constexpr size_t EF_BYTES = (size_t)NBLK * 64 * 16;        // 256 KB
constexpr size_t WF_OFF = EF_OFF + EF_BYTES;               // 6.42 MB

static __device__ __forceinline__ uint4 pack8h(const float* f) {
    unsigned short u[8];
#pragma unroll
    for (int i = 0; i < 8; ++i) {
        _Float16 h = (_Float16)f[i];
        u[i] = __builtin_bit_cast(unsigned short, h);
    }
    uint4 r;
    r.x = (unsigned)u[0] | ((unsigned)u[1] << 16);
    r.y = (unsigned)u[2] | ((unsigned)u[3] << 16);
    r.z = (unsigned)u[4] | ((unsigned)u[5] << 16);
    r.w = (unsigned)u[6] | ((unsigned)u[7] << 16);
    return r;
}

// Merged prep: W -> fp16 A-operand fragments, then emb[seq] -> fp16 B-frags.
__global__ __launch_bounds__(256) void prep_frags(
    const float* __restrict__ W,
    const int*   __restrict__ seq,
    const float* __restrict__ emb,
    uint4* __restrict__ Wf,
    uint4* __restrict__ Ef,
    int V)
{
    const int g = blockIdx.x * 256 + threadIdx.x;
    if (g < V_TILES * 64) {
        const int lane = g & 63;
        const int tile = g >> 6;
        int col = tile * 16 + (lane & 15);
        if (col >= V) col = V - 1;                     // pad clamp (masked later)
        const int k0 = (lane >> 4) * 8;
        const float* wp = W + (size_t)col * 32 + k0;
        float f[8];
        *reinterpret_cast<float4*>(f)     = *reinterpret_cast<const float4*>(wp);
        *reinterpret_cast<float4*>(f + 4) = *reinterpret_cast<const float4*>(wp + 4);
        Wf[g] = pack8h(f);
    } else {
        const int g2   = g - V_TILES * 64;             // NBLK*64
        const int lane = g2 & 63;
        const int c    = g2 >> 6;
        const int row  = c * 16 + (lane & 15);
        const int k0   = (lane >> 4) * 8;
        const int idx  = seq[row];
        const float* ep = emb + (size_t)idx * 32 + k0;
        float f[8];
        *reinterpret_cast<float4*>(f)     = *reinterpret_cast<const float4*>(ep);
        *reinterpret_cast<float4*>(f + 4) = *reinterpret_cast<const float4*>(ep + 4);
        Ef[g2] = pack8h(f);
    }
}

__global__ __launch_bounds__(TPB) void bigram_main(
    const uint4* __restrict__ Wf,
    const float* __restrict__ bias,
    const uint4* __restrict__ Ef,
    float*       __restrict__ logits,
    float*       __restrict__ rowsum,
    int V)
{
    __shared__ float ebuf[2][ROWS_PB][PSTR];   // ~136.5 KB
    __shared__ float lsum[WAVES][ROWS_PB];

    const int tid  = threadIdx.x;
    const int lane = tid & 63;
    const int wid  = tid >> 6;
    const int lgrp = lane >> 4;
    const int lcol = lane & 15;
    const int b    = blockIdx.x;

    const f16x8 E = __builtin_bit_cast(f16x8, Ef[(size_t)b * 64 + lane]);
    const int wcol = wid * (TILES * 16);
    float rs = 0.f;

    // Shifts: LshW = shift of the row this LANE computes (row lcol);
    //         Lsh  = shift of the row this WAVE stores (row wid).
    // Row n shift = (21*n)&31 with n = b*16 + r  ->  (16*b + 21*r)&31.
    const int LshW = (16 * b + 21 * lcol) & 31;
    const int Lsh  = (16 * b + 21 * wid) & 31;
    const int n_row = b * ROWS_PB + wid;
    float* rowbase  = logits + (size_t)n_row * V;

    // Prologue: window 0 W frags + bias (window 0 never tail).
    uint4 Wc[TILES]; f32x4 Bc[TILES];
#pragma unroll
    for (int t = 0; t < TILES; ++t) {
        Wc[t] = Wf[(size_t)(wid * TILES + t) * 64 + lane];
        const float4 b4 = *reinterpret_cast<const float4*>(
            bias + wcol + t * 16 + lgrp * 4);
        Bc[t] = f32x4{b4.x, b4.y, b4.z, b4.w};
    }

    for (int s = 0; s < NWIN; ++s) {
        const int  cbase = s * WIN;
        const bool last  = (s == NWIN - 1);
        float (*cbuf)[PSTR] = ebuf[s & 1];         // compute+store buffer
        float (*nbuf)[PSTR] = ebuf[(s + 1) & 1];   // next buffer (carry dest)

        // ---- distance-1 prefetch of next window's W frags + bias ----
        const int  sp    = (s + 1 < NWIN) ? s + 1 : s;
        const bool ptail = (sp == NWIN - 1);
        uint4 Wn[TILES]; f32x4 Bn[TILES];
#pragma unroll
        for (int t = 0; t < TILES; ++t)
            Wn[t] = Wf[(size_t)(sp * (WIN / 16) + wid * TILES + t) * 64 + lane];
#pragma unroll
        for (int t = 0; t < TILES; ++t) {
            const int c0 = sp * WIN + wcol + t * 16 + lgrp * 4;
            if (!ptail) {
                const float4 b4 = *reinterpret_cast<const float4*>(bias + c0);
                Bn[t] = f32x4{b4.x, b4.y, b4.z, b4.w};
            } else {
#pragma unroll
                for (int j = 0; j < 4; ++j) {
                    const int c = c0 + j;
                    Bn[t][j] = bias[c < V ? c : V - 1];
                }
            }
        }

        // ---- compute: MFMA (bias C-init) + exp + SHIFTED LDS write ----
        // Column c -> cbuf[row][32 + (c-cbase) + LshW]; all writes stay in cbuf
        // (idx <= 32+1023+31 = 1086 < PSTR). Tail [1056,1088) carried later.
#pragma unroll
        for (int t = 0; t < TILES; ++t) {
            const f32x4 acc = __builtin_amdgcn_mfma_f32_16x16x32_f16(
                __builtin_bit_cast(f16x8, Wc[t]), E, Bc[t], 0, 0, 0);
            if (!last) {
                rs += __expf(acc[0]) + __expf(acc[1]) +
                      __expf(acc[2]) + __expf(acc[3]);
            } else {
                const int c0 = cbase + wcol + t * 16 + lgrp * 4;
#pragma unroll
                for (int j = 0; j < 4; ++j)
                    if (c0 + j < V) rs += __expf(acc[j]);
            }
            const int base = 32 + wcol + t * 16 + lgrp * 4 + LshW;
            cbuf[lcol][base + 0] = acc[0];
            cbuf[lcol][base + 1] = acc[1];
            cbuf[lcol][base + 2] = acc[2];
            cbuf[lcol][base + 3] = acc[3];
        }

        // The ONLY barrier per window.
        asm volatile("s_waitcnt lgkmcnt(0)" ::: "memory");
        __builtin_amdgcn_s_barrier();
        __builtin_amdgcn_sched_barrier(0);

        // ---- store phase: aligned b128 LDS reads + nt full-line stores ----
        {
#pragma unroll
            for (int i = 0; i < 4; ++i) {
                const int colL = i * 256 + lane * 4;
                const f32x4 v = *reinterpret_cast<const f32x4*>(&cbuf[wid][32 + colL]);
                const int gcol = cbase - Lsh + colL;
                if (s == 0 && i == 0) {
#pragma unroll
                    for (int j = 0; j < 4; ++j)
                        if (gcol + j >= 0)
                            __builtin_nontemporal_store(v[j], rowbase + gcol + j);
                } else if (last && i == 3) {
#pragma unroll
                    for (int j = 0; j < 4; ++j)
                        if (gcol + j < V)
                            __builtin_nontemporal_store(v[j], rowbase + gcol + j);
                } else {
                    __builtin_nontemporal_store(
                        v, reinterpret_cast<f32x4*>(rowbase + gcol));
                }
            }
            // Carry: this window's tail (idx >= 1056) -> next buffer's prefix.
            // Only k < Lsh meaningful; compute(s+1) fills [32+Lsh, ...) itself.
            if (lane < Lsh)
                nbuf[wid][32 + lane] = cbuf[wid][1056 + lane];
        }
        // NO second barrier: compute(s+1) writes nbuf at [32+LshW, ...), which
        // is disjoint from this carry ([32, 32+Lsh) of the same row), and
        // store(s) reads only cbuf.

#pragma unroll
        for (int t = 0; t < TILES; ++t) { Wc[t] = Wn[t]; Bc[t] = Bn[t]; }
    }

    // In-block rowsum.
    rs += __shfl_xor(rs, 16, 64);
    rs += __shfl_xor(rs, 32, 64);
    if (lane < 16) lsum[wid][lcol] = rs;
    __syncthreads();
    if (tid < ROWS_PB) {
        float t = 0.f;
#pragma unroll
        for (int w = 0; w < WAVES; ++w) t += lsum[w][tid];
        rowsum[b * ROWS_PB + tid] = t;
    }
}

// Single-block loss: no atomics, no memset.
// loss = mean( log(rowsum[n]) - (dot(emb[seq[n]], W[pred[n]]) + b[pred[n]]) )
__global__ __launch_bounds__(1024) void bigram_loss(
    const int*   __restrict__ seq,
    const int*   __restrict__ pred,
    const float* __restrict__ emb,
    const float* __restrict__ W,
    const float* __restrict__ bias,
    const float* __restrict__ rowsum,
    float*       __restrict__ loss,
    int N)
{
    const int tid = threadIdx.x;
    float local = 0.f;
    for (int n = tid; n < N; n += 1024) {
        const int r = seq[n], t = pred[n];
        const float4* e4 = reinterpret_cast<const float4*>(emb + (size_t)r * 32);
        const float4* w4 = reinterpret_cast<const float4*>(W + (size_t)t * 32);
        float d = bias[t];
#pragma unroll
        for (int i = 0; i < 8; ++i) {
            const float4 e = e4[i], w = w4[i];
            d += e.x * w.x + e.y * w.y + e.z * w.z + e.w * w.w;
        }
        local += __logf(rowsum[n]) - d;
    }
#pragma unroll
    for (int off = 32; off >= 1; off >>= 1) local += __shfl_xor(local, off, 64);
    __shared__ float r16[16];
    if ((tid & 63) == 0) r16[tid >> 6] = local;
    __syncthreads();
    if (tid == 0) {
        float s = 0.f;
#pragma unroll
        for (int w = 0; w < 16; ++w) s += r16[w];
        loss[0] = s / (float)N;
    }
}

extern "C" void kernel_launch(void* const* d_in, const int* in_sizes, int n_in,
                              void* d_out, int out_size, void* d_ws, size_t ws_size,
                              hipStream_t stream)
{
    const int*   seq  = (const int*)d_in[0];
    const int*   pred = (const int*)d_in[1];
    const float* emb  = (const float*)d_in[2];
    const float* W    = (const float*)d_in[3];
    const float* bias = (const float*)d_in[4];

    const int N = in_sizes[0];      // 4096
    const int V = in_sizes[4];      // 100277

    float* logits = (float*)d_out;
    float* loss   = logits + (size_t)N * V;

    char*  ws     = (char*)d_ws;
    float* rowsum = (float*)(ws + RS_OFF);
    uint4* Ef     = (uint4*)(ws + EF_OFF);
    uint4* Wf     = (uint4*)(ws + WF_OFF);

    const int prepTotal = V_TILES * 64 + NBLK * 64;   // 417792 -> 1632 blocks
    hipLaunchKernelGGL(prep_frags, dim3(prepTotal / 256), dim3(256), 0, stream,
                       W, seq, emb, Wf, Ef, V);

    hipLaunchKernelGGL(bigram_main, dim3(NBLK), dim3(TPB), 0, stream,
                       Wf, bias, Ef, logits, rowsum, V);

    hipLaunchKernelGGL(bigram_loss, dim3(1), dim3(1024), 0, stream,
                       seq, pred, emb, W, bias, rowsum, loss, N);
}